// Round 1
// baseline (863.490 us; speedup 1.0000x reference)
//
#include <hip/hip_runtime.h>

// ---------------------------------------------------------------------------
// Sparse MS-Deformable Attention, f32, correctness-first round.
// Reformulation: bilerp raw v rows (256ch), attn-weighted aggregate per
// (n,h), THEN project with W_val (softmax weights sum to 1 so b_val passes
// through unchanged). Avoids the 91-GFLOP full-map value projection.
// ---------------------------------------------------------------------------

// Y[n, 0:M] = X[n, 0:256] @ W[256, M] + bias ; 32 rows per block, M threads.
template<int M>
__global__ __launch_bounds__(M)
void gemm_nk256(const float* __restrict__ X, const float* __restrict__ W,
                const float* __restrict__ bias, float* __restrict__ Y) {
    __shared__ float xt[32 * 256];
    const int c = threadIdx.x;
    const long row0 = (long)blockIdx.x * 32;
    const float4* src = (const float4*)(X + row0 * 256);
    float4* dst4 = (float4*)xt;
    for (int i = c; i < 32 * 64; i += M) dst4[i] = src[i];
    __syncthreads();
    float acc[32];
#pragma unroll
    for (int qi = 0; qi < 32; ++qi) acc[qi] = 0.f;
    for (int k4 = 0; k4 < 64; ++k4) {
        const float w0 = W[(k4 * 4 + 0) * M + c];
        const float w1 = W[(k4 * 4 + 1) * M + c];
        const float w2 = W[(k4 * 4 + 2) * M + c];
        const float w3 = W[(k4 * 4 + 3) * M + c];
#pragma unroll
        for (int qi = 0; qi < 32; ++qi) {
            const float4 q = *(const float4*)&xt[qi * 256 + k4 * 4];
            float a = acc[qi];
            a = fmaf(q.x, w0, a);
            a = fmaf(q.y, w1, a);
            a = fmaf(q.z, w2, a);
            a = fmaf(q.w, w3, a);
            acc[qi] = a;
        }
    }
    const float bv = bias[c];
#pragma unroll
    for (int qi = 0; qi < 32; ++qi)
        Y[(row0 + qi) * M + c] = acc[qi] + bv;
}

// In-place softmax over rows of 16 (layout: nrows x 16 contiguous).
__global__ void softmax16(float* __restrict__ A, int nrows) {
    const int r = blockIdx.x * blockDim.x + threadIdx.x;
    if (r >= nrows) return;
    float4* p = (float4*)(A + (size_t)r * 16);
    float4 v[4] = {p[0], p[1], p[2], p[3]};
    float m = -1e30f;
#pragma unroll
    for (int i = 0; i < 4; ++i) {
        m = fmaxf(m, fmaxf(fmaxf(v[i].x, v[i].y), fmaxf(v[i].z, v[i].w)));
    }
    float s = 0.f;
#pragma unroll
    for (int i = 0; i < 4; ++i) {
        v[i].x = expf(v[i].x - m); s += v[i].x;
        v[i].y = expf(v[i].y - m); s += v[i].y;
        v[i].z = expf(v[i].z - m); s += v[i].z;
        v[i].w = expf(v[i].w - m); s += v[i].w;
    }
    const float inv = 1.f / s;
#pragma unroll
    for (int i = 0; i < 4; ++i) {
        v[i].x *= inv; v[i].y *= inv; v[i].z *= inv; v[i].w *= inv;
        p[i] = v[i];
    }
}

// One block per query. 256 threads = 8 heads x 32 lanes; lane owns 8 raw
// channels. Bilerp raw v rows, attn-weighted accumulate, then fused W_val
// projection (256->256 with per-head 32-col slices) -> val_out.
__global__ __launch_bounds__(256)
void sample_agg_proj(const float* __restrict__ offs_all,
                     const float* __restrict__ attn_all,
                     const float* __restrict__ refpts,
                     const int* __restrict__ qoff, int n_off,
                     const float* __restrict__ v0, const float* __restrict__ v1,
                     const float* __restrict__ v2, const float* __restrict__ v3,
                     const float* __restrict__ W_val, const float* __restrict__ b_val,
                     float* __restrict__ val_out) {
    __shared__ float sOff[256];
    __shared__ float sAttn[128];
    __shared__ float sAgg[8 * 256];
    const int n = blockIdx.x;
    const int tid = threadIdx.x;

    if (tid < 64) ((float4*)sOff)[tid] = ((const float4*)(offs_all + (size_t)n * 256))[tid];
    else if (tid < 96) ((float4*)sAttn)[tid - 64] = ((const float4*)(attn_all + (size_t)n * 128))[tid - 64];
    __syncthreads();

    int b = 0;
    for (int i = 1; i < n_off; ++i) if (n >= qoff[i]) b = i;
    const float ri = refpts[2 * n];
    const float rj = refpts[2 * n + 1];
    const int h = tid >> 5, g = tid & 31;

    float acc[8];
#pragma unroll
    for (int j = 0; j < 8; ++j) acc[j] = 0.f;

    const float* vptr[4] = {v0, v1, v2, v3};
    const int dims[4] = {64, 128, 256, 512};

#pragma unroll
    for (int l = 0; l < 4; ++l) {
        const int hw = dims[l];
        const float sc = (float)hw * (1.0f / 512.0f);
        const float* __restrict__ vb = vptr[l] + (size_t)b * hw * hw * 256 + g * 8;
#pragma unroll
        for (int p = 0; p < 4; ++p) {
            const int oi = ((h * 4 + l) * 4 + p) * 2;
            const float fi = (ri + sOff[oi]) * sc;
            const float fj = (rj + sOff[oi + 1]) * sc;
            const float a = sAttn[(h * 4 + l) * 4 + p];
            const float sci = fmaxf(fi - 0.5f, 0.f);
            const float scj = fmaxf(fj - 0.5f, 0.f);
            const float fl_i = floorf(sci), fl_j = floorf(scj);
            const int i0 = (int)fl_i, j0 = (int)fl_j;
            const float fri = sci - fl_i, frj = scj - fl_j;
            const int i0c = min(i0, hw - 1), i1c = min(i0 + 1, hw - 1);
            const int j0c = min(j0, hw - 1), j1c = min(j0 + 1, hw - 1);
            const float w00 = (1.f - fri) * (1.f - frj) * a;
            const float w01 = (1.f - fri) * frj * a;
            const float w10 = fri * (1.f - frj) * a;
            const float w11 = fri * frj * a;
            const float* r0 = vb + (size_t)i0c * hw * 256;
            const float* r1 = vb + (size_t)i1c * hw * 256;
#define CORNER(RP, JC, W)                                                \
            {                                                            \
                const float4* cp = (const float4*)((RP) + (size_t)(JC) * 256); \
                const float4 u = cp[0], w4 = cp[1];                      \
                acc[0] = fmaf((W), u.x,  acc[0]);                        \
                acc[1] = fmaf((W), u.y,  acc[1]);                        \
                acc[2] = fmaf((W), u.z,  acc[2]);                        \
                acc[3] = fmaf((W), u.w,  acc[3]);                        \
                acc[4] = fmaf((W), w4.x, acc[4]);                        \
                acc[5] = fmaf((W), w4.y, acc[5]);                        \
                acc[6] = fmaf((W), w4.z, acc[6]);                        \
                acc[7] = fmaf((W), w4.w, acc[7]);                        \
            }
            CORNER(r0, j0c, w00)
            CORNER(r0, j1c, w01)
            CORNER(r1, j0c, w10)
            CORNER(r1, j1c, w11)
#undef CORNER
        }
    }

    float4* sa4 = (float4*)(sAgg + h * 256 + g * 8);
    sa4[0] = make_float4(acc[0], acc[1], acc[2], acc[3]);
    sa4[1] = make_float4(acc[4], acc[5], acc[6], acc[7]);
    __syncthreads();

    // projection: out channel c2 = tid, uses head h2 = c2/32 aggregate.
    const int c2 = tid, h2 = tid >> 5;
    float s = b_val[c2];
    const float4* agr = (const float4*)(sAgg + h2 * 256);
    for (int k4 = 0; k4 < 64; ++k4) {
        const float4 av = agr[k4];
        s = fmaf(av.x, W_val[(k4 * 4 + 0) * 256 + c2], s);
        s = fmaf(av.y, W_val[(k4 * 4 + 1) * 256 + c2], s);
        s = fmaf(av.z, W_val[(k4 * 4 + 2) * 256 + c2], s);
        s = fmaf(av.w, W_val[(k4 * 4 + 3) * 256 + c2], s);
    }
    val_out[(size_t)n * 256 + c2] = s;
}

extern "C" void kernel_launch(void* const* d_in, const int* in_sizes, int n_in,
                              void* d_out, int out_size, void* d_ws, size_t ws_size,
                              hipStream_t stream) {
    const float* query  = (const float*)d_in[0];
    const int*   qoff   = (const int*)d_in[1];
    const float* refp   = (const float*)d_in[2];
    const float* v0     = (const float*)d_in[3];
    const float* v1     = (const float*)d_in[4];
    const float* v2     = (const float*)d_in[5];
    const float* v3     = (const float*)d_in[6];
    const float* W_off  = (const float*)d_in[7];
    const float* b_off  = (const float*)d_in[8];
    const float* W_attn = (const float*)d_in[9];
    const float* b_attn = (const float*)d_in[10];
    const float* W_val  = (const float*)d_in[11];
    const float* b_val  = (const float*)d_in[12];
    const float* W_out  = (const float*)d_in[13];
    const float* b_out  = (const float*)d_in[14];
    float* out = (float*)d_out;

    const int N = in_sizes[0] / 256;   // 16384
    const int n_off = in_sizes[1];     // 2

    float* P1off  = (float*)d_ws;                 // N*256 f32
    float* P1attn = P1off + (size_t)N * 256;      // N*128 f32

    gemm_nk256<256><<<N / 32, 256, 0, stream>>>(query, W_off, b_off, P1off);
    gemm_nk256<128><<<N / 32, 128, 0, stream>>>(query, W_attn, b_attn, P1attn);
    softmax16<<<(N * 8 + 255) / 256, 256, 0, stream>>>(P1attn, N * 8);
    // val_out staged in d_out (fully overwritten by final GEMM, which is
    // safe in-place: each block stages its own 32 rows into LDS first).
    sample_agg_proj<<<N, 256, 0, stream>>>(P1off, P1attn, refp, qoff, n_off,
                                           v0, v1, v2, v3, W_val, b_val, out);
    gemm_nk256<256><<<N / 32, 256, 0, stream>>>(out, W_out, b_out, out);
}

// Round 2
// 837.221 us; speedup vs baseline: 1.0314x; 1.0314x over previous
//
#include <hip/hip_runtime.h>

// ---------------------------------------------------------------------------
// Sparse MS-Deformable Attention, f32.
// Round 2: sample_agg_proj restructured for memory-level parallelism —
// precompute corner offsets/weights, batch-load 2 points (16 float4) into
// registers before accumulating. Was latency-bound at 40 VGPR / 1-2
// outstanding loads per lane.
// ---------------------------------------------------------------------------

// Y[n, 0:M] = X[n, 0:256] @ W[256, M] + bias ; 32 rows per block, M threads.
template<int M>
__global__ __launch_bounds__(M)
void gemm_nk256(const float* __restrict__ X, const float* __restrict__ W,
                const float* __restrict__ bias, float* __restrict__ Y) {
    __shared__ float xt[32 * 256];
    const int c = threadIdx.x;
    const long row0 = (long)blockIdx.x * 32;
    const float4* src = (const float4*)(X + row0 * 256);
    float4* dst4 = (float4*)xt;
    for (int i = c; i < 32 * 64; i += M) dst4[i] = src[i];
    __syncthreads();
    float acc[32];
#pragma unroll
    for (int qi = 0; qi < 32; ++qi) acc[qi] = 0.f;
    for (int k4 = 0; k4 < 64; ++k4) {
        const float w0 = W[(k4 * 4 + 0) * M + c];
        const float w1 = W[(k4 * 4 + 1) * M + c];
        const float w2 = W[(k4 * 4 + 2) * M + c];
        const float w3 = W[(k4 * 4 + 3) * M + c];
#pragma unroll
        for (int qi = 0; qi < 32; ++qi) {
            const float4 q = *(const float4*)&xt[qi * 256 + k4 * 4];
            float a = acc[qi];
            a = fmaf(q.x, w0, a);
            a = fmaf(q.y, w1, a);
            a = fmaf(q.z, w2, a);
            a = fmaf(q.w, w3, a);
            acc[qi] = a;
        }
    }
    const float bv = bias[c];
#pragma unroll
    for (int qi = 0; qi < 32; ++qi)
        Y[(row0 + qi) * M + c] = acc[qi] + bv;
}

// In-place softmax over rows of 16 (layout: nrows x 16 contiguous).
__global__ void softmax16(float* __restrict__ A, int nrows) {
    const int r = blockIdx.x * blockDim.x + threadIdx.x;
    if (r >= nrows) return;
    float4* p = (float4*)(A + (size_t)r * 16);
    float4 v[4] = {p[0], p[1], p[2], p[3]};
    float m = -1e30f;
#pragma unroll
    for (int i = 0; i < 4; ++i) {
        m = fmaxf(m, fmaxf(fmaxf(v[i].x, v[i].y), fmaxf(v[i].z, v[i].w)));
    }
    float s = 0.f;
#pragma unroll
    for (int i = 0; i < 4; ++i) {
        v[i].x = expf(v[i].x - m); s += v[i].x;
        v[i].y = expf(v[i].y - m); s += v[i].y;
        v[i].z = expf(v[i].z - m); s += v[i].z;
        v[i].w = expf(v[i].w - m); s += v[i].w;
    }
    const float inv = 1.f / s;
#pragma unroll
    for (int i = 0; i < 4; ++i) {
        v[i].x *= inv; v[i].y *= inv; v[i].z *= inv; v[i].w *= inv;
        p[i] = v[i];
    }
}

// One block per query. 256 threads = 8 heads x 32 lanes; lane owns 8 raw
// channels. Bilerp raw v rows, attn-weighted accumulate, then fused W_val
// projection (256->256 with per-head 32-col slices) -> val_out.
__global__ __launch_bounds__(256)
void sample_agg_proj(const float* __restrict__ offs_all,
                     const float* __restrict__ attn_all,
                     const float* __restrict__ refpts,
                     const int* __restrict__ qoff, int n_off,
                     const float* __restrict__ v0, const float* __restrict__ v1,
                     const float* __restrict__ v2, const float* __restrict__ v3,
                     const float* __restrict__ W_val, const float* __restrict__ b_val,
                     float* __restrict__ val_out) {
    __shared__ float sOff[256];
    __shared__ float sAttn[128];
    __shared__ float sAgg[8 * 256];
    const int n = blockIdx.x;
    const int tid = threadIdx.x;

    if (tid < 64) ((float4*)sOff)[tid] = ((const float4*)(offs_all + (size_t)n * 256))[tid];
    else if (tid < 96) ((float4*)sAttn)[tid - 64] = ((const float4*)(attn_all + (size_t)n * 128))[tid - 64];
    __syncthreads();

    int b = 0;
    for (int i = 1; i < n_off; ++i) if (n >= qoff[i]) b = i;
    const float ri = refpts[2 * n];
    const float rj = refpts[2 * n + 1];
    const int h = tid >> 5, g = tid & 31;

    float acc[8];
#pragma unroll
    for (int j = 0; j < 8; ++j) acc[j] = 0.f;

    const float* vptr[4] = {v0, v1, v2, v3};
    const int dims[4] = {64, 128, 256, 512};

#pragma unroll
    for (int l = 0; l < 4; ++l) {
        const int hw = dims[l];
        const float sc = (float)hw * (1.0f / 512.0f);
        const float* __restrict__ vb = vptr[l] + (size_t)b * hw * hw * 256 + g * 8;

        // --- phase 1: descriptors for all 4 points (register-resident) ---
        int   coff[4][4];   // corner float-offsets rel. to vb
        float wgt[4][4];    // attn-scaled bilinear weights
#pragma unroll
        for (int p = 0; p < 4; ++p) {
            const int oi = ((h * 4 + l) * 4 + p) * 2;
            const float fi = (ri + sOff[oi]) * sc;
            const float fj = (rj + sOff[oi + 1]) * sc;
            const float a = sAttn[(h * 4 + l) * 4 + p];
            const float sci = fmaxf(fi - 0.5f, 0.f);
            const float scj = fmaxf(fj - 0.5f, 0.f);
            const float fl_i = floorf(sci), fl_j = floorf(scj);
            const int i0 = (int)fl_i, j0 = (int)fl_j;
            const float fri = sci - fl_i, frj = scj - fl_j;
            const int i0c = min(i0, hw - 1), i1c = min(i0 + 1, hw - 1);
            const int j0c = min(j0, hw - 1), j1c = min(j0 + 1, hw - 1);
            coff[p][0] = (i0c * hw + j0c) * 256;
            coff[p][1] = (i0c * hw + j1c) * 256;
            coff[p][2] = (i1c * hw + j0c) * 256;
            coff[p][3] = (i1c * hw + j1c) * 256;
            const float uw = 1.f - fri, lw = 1.f - frj;
            wgt[p][0] = uw * lw * a;
            wgt[p][1] = uw * frj * a;
            wgt[p][2] = fri * lw * a;
            wgt[p][3] = fri * frj * a;
        }

        // --- phase 2: batch-load 2 points (16 float4 in flight), then FMA ---
#pragma unroll
        for (int pp = 0; pp < 4; pp += 2) {
            float4 buf[16];
#pragma unroll
            for (int q = 0; q < 2; ++q) {
#pragma unroll
                for (int cr = 0; cr < 4; ++cr) {
                    const float4* cp = (const float4*)(vb + (size_t)coff[pp + q][cr]);
                    buf[q * 8 + cr * 2 + 0] = cp[0];
                    buf[q * 8 + cr * 2 + 1] = cp[1];
                }
            }
#pragma unroll
            for (int q = 0; q < 2; ++q) {
#pragma unroll
                for (int cr = 0; cr < 4; ++cr) {
                    const float wv = wgt[pp + q][cr];
                    const float4 u  = buf[q * 8 + cr * 2 + 0];
                    const float4 w4 = buf[q * 8 + cr * 2 + 1];
                    acc[0] = fmaf(wv, u.x,  acc[0]);
                    acc[1] = fmaf(wv, u.y,  acc[1]);
                    acc[2] = fmaf(wv, u.z,  acc[2]);
                    acc[3] = fmaf(wv, u.w,  acc[3]);
                    acc[4] = fmaf(wv, w4.x, acc[4]);
                    acc[5] = fmaf(wv, w4.y, acc[5]);
                    acc[6] = fmaf(wv, w4.z, acc[6]);
                    acc[7] = fmaf(wv, w4.w, acc[7]);
                }
            }
        }
    }

    float4* sa4 = (float4*)(sAgg + h * 256 + g * 8);
    sa4[0] = make_float4(acc[0], acc[1], acc[2], acc[3]);
    sa4[1] = make_float4(acc[4], acc[5], acc[6], acc[7]);
    __syncthreads();

    // projection: out channel c2 = tid, uses head h2 = c2/32 aggregate.
    const int c2 = tid, h2 = tid >> 5;
    float s = b_val[c2];
    const float4* agr = (const float4*)(sAgg + h2 * 256);
    for (int k4 = 0; k4 < 64; ++k4) {
        const float4 av = agr[k4];
        s = fmaf(av.x, W_val[(k4 * 4 + 0) * 256 + c2], s);
        s = fmaf(av.y, W_val[(k4 * 4 + 1) * 256 + c2], s);
        s = fmaf(av.z, W_val[(k4 * 4 + 2) * 256 + c2], s);
        s = fmaf(av.w, W_val[(k4 * 4 + 3) * 256 + c2], s);
    }
    val_out[(size_t)n * 256 + c2] = s;
}

extern "C" void kernel_launch(void* const* d_in, const int* in_sizes, int n_in,
                              void* d_out, int out_size, void* d_ws, size_t ws_size,
                              hipStream_t stream) {
    const float* query  = (const float*)d_in[0];
    const int*   qoff   = (const int*)d_in[1];
    const float* refp   = (const float*)d_in[2];
    const float* v0     = (const float*)d_in[3];
    const float* v1     = (const float*)d_in[4];
    const float* v2     = (const float*)d_in[5];
    const float* v3     = (const float*)d_in[6];
    const float* W_off  = (const float*)d_in[7];
    const float* b_off  = (const float*)d_in[8];
    const float* W_attn = (const float*)d_in[9];
    const float* b_attn = (const float*)d_in[10];
    const float* W_val  = (const float*)d_in[11];
    const float* b_val  = (const float*)d_in[12];
    const float* W_out  = (const float*)d_in[13];
    const float* b_out  = (const float*)d_in[14];
    float* out = (float*)d_out;

    const int N = in_sizes[0] / 256;   // 16384
    const int n_off = in_sizes[1];     // 2

    float* P1off  = (float*)d_ws;                 // N*256 f32
    float* P1attn = P1off + (size_t)N * 256;      // N*128 f32

    gemm_nk256<256><<<N / 32, 256, 0, stream>>>(query, W_off, b_off, P1off);
    gemm_nk256<128><<<N / 32, 128, 0, stream>>>(query, W_attn, b_attn, P1attn);
    softmax16<<<(N * 8 + 255) / 256, 256, 0, stream>>>(P1attn, N * 8);
    // val_out staged in d_out (fully overwritten by final GEMM, which is
    // safe in-place: each block stages its own 32 rows into LDS first).
    sample_agg_proj<<<N, 256, 0, stream>>>(P1off, P1attn, refp, qoff, n_off,
                                           v0, v1, v2, v3, W_val, b_val, out);
    gemm_nk256<256><<<N / 32, 256, 0, stream>>>(out, W_out, b_out, out);
}

// Round 3
// 668.784 us; speedup vs baseline: 1.2911x; 1.2519x over previous
//
#include <hip/hip_runtime.h>

// ---------------------------------------------------------------------------
// Sparse MS-Deformable Attention, f32.
// Round 3: (a) asm-volatile register fences pin 8 dwordx4 corner loads in
// flight per point (round-2 attempt was dissolved by the scheduler, VGPR
// stayed 40); (b) 4 queries per block amortize fused W_val projection 4x;
// (c) softmax fused into the sampler (logits read directly).
// ---------------------------------------------------------------------------

typedef float f32x4 __attribute__((ext_vector_type(4)));

// Y[n, 0:M] = X[n, 0:256] @ W[256, M] + bias ; 32 rows per block, M threads.
template<int M>
__global__ __launch_bounds__(M)
void gemm_nk256(const float* __restrict__ X, const float* __restrict__ W,
                const float* __restrict__ bias, float* __restrict__ Y) {
    __shared__ float xt[32 * 256];
    const int c = threadIdx.x;
    const long row0 = (long)blockIdx.x * 32;
    const float4* src = (const float4*)(X + row0 * 256);
    float4* dst4 = (float4*)xt;
    for (int i = c; i < 32 * 64; i += M) dst4[i] = src[i];
    __syncthreads();
    float acc[32];
#pragma unroll
    for (int qi = 0; qi < 32; ++qi) acc[qi] = 0.f;
    for (int k4 = 0; k4 < 64; ++k4) {
        const float w0 = W[(k4 * 4 + 0) * M + c];
        const float w1 = W[(k4 * 4 + 1) * M + c];
        const float w2 = W[(k4 * 4 + 2) * M + c];
        const float w3 = W[(k4 * 4 + 3) * M + c];
#pragma unroll
        for (int qi = 0; qi < 32; ++qi) {
            const float4 q = *(const float4*)&xt[qi * 256 + k4 * 4];
            float a = acc[qi];
            a = fmaf(q.x, w0, a);
            a = fmaf(q.y, w1, a);
            a = fmaf(q.z, w2, a);
            a = fmaf(q.w, w3, a);
            acc[qi] = a;
        }
    }
    const float bv = bias[c];
#pragma unroll
    for (int qi = 0; qi < 32; ++qi)
        Y[(row0 + qi) * M + c] = acc[qi] + bv;
}

// 4 queries per block. 256 threads = 8 heads x 32 lanes; lane owns 8 raw
// channels. Softmax(logits) in LDS, bilerp raw v rows with pinned-MLP corner
// loads, attn-weighted accumulate -> sAgg, fused W_val projection.
#define QPB 4
__global__ __launch_bounds__(256, 4)
void sample_agg_proj(const float* __restrict__ offs_all,
                     const float* __restrict__ logits_all,
                     const float* __restrict__ refpts,
                     const int* __restrict__ qoff, int n_off,
                     const float* __restrict__ v0, const float* __restrict__ v1,
                     const float* __restrict__ v2, const float* __restrict__ v3,
                     const float* __restrict__ W_val, const float* __restrict__ b_val,
                     float* __restrict__ val_out) {
    __shared__ float sOff[QPB][256];
    __shared__ float sAttn[QPB][128];
    __shared__ float sRef[QPB][2];
    __shared__ float sAgg[QPB][8][256];
    const int n0 = blockIdx.x * QPB;
    const int tid = threadIdx.x;

    ((f32x4*)sOff)[tid] = ((const f32x4*)(offs_all + (size_t)n0 * 256))[tid];
    if (tid < QPB * 32) ((f32x4*)sAttn)[tid] = ((const f32x4*)(logits_all + (size_t)n0 * 128))[tid];
    if (tid < QPB * 2) ((float*)sRef)[tid] = refpts[(size_t)n0 * 2 + tid];
    __syncthreads();

    // softmax over 16 for each of QPB*8 (q,h) rows
    if (tid < QPB * 8) {
        float* row = &sAttn[tid >> 3][(tid & 7) * 16];
        float m = -1e30f;
#pragma unroll
        for (int i = 0; i < 16; ++i) m = fmaxf(m, row[i]);
        float s = 0.f;
#pragma unroll
        for (int i = 0; i < 16; ++i) { const float e = expf(row[i] - m); row[i] = e; s += e; }
        const float inv = 1.f / s;
#pragma unroll
        for (int i = 0; i < 16; ++i) row[i] *= inv;
    }
    __syncthreads();

    const int h = tid >> 5, g = tid & 31;
    const float* vptr[4] = {v0, v1, v2, v3};
    const int dims[4] = {64, 128, 256, 512};

    for (int q = 0; q < QPB; ++q) {
        const int n = n0 + q;
        int b = 0;
        for (int i = 1; i < n_off; ++i) if (n >= qoff[i]) b = i;
        const float ri = sRef[q][0];
        const float rj = sRef[q][1];

        float acc[8];
#pragma unroll
        for (int j = 0; j < 8; ++j) acc[j] = 0.f;

#pragma unroll
        for (int l = 0; l < 4; ++l) {
            const int hw = dims[l];
            const float sc = (float)hw * (1.0f / 512.0f);
            const float* __restrict__ vb = vptr[l] + (size_t)b * hw * hw * 256 + g * 8;

            int   coff[4][4];
            float wgt[4][4];
#pragma unroll
            for (int p = 0; p < 4; ++p) {
                const int oi = ((h * 4 + l) * 4 + p) * 2;
                const float fi = (ri + sOff[q][oi]) * sc;
                const float fj = (rj + sOff[q][oi + 1]) * sc;
                const float a = sAttn[q][(h * 4 + l) * 4 + p];
                const float sci = fmaxf(fi - 0.5f, 0.f);
                const float scj = fmaxf(fj - 0.5f, 0.f);
                const float fl_i = floorf(sci), fl_j = floorf(scj);
                const int i0 = (int)fl_i, j0 = (int)fl_j;
                const float fri = sci - fl_i, frj = scj - fl_j;
                const int i0c = min(i0, hw - 1), i1c = min(i0 + 1, hw - 1);
                const int j0c = min(j0, hw - 1), j1c = min(j0 + 1, hw - 1);
                coff[p][0] = (i0c * hw + j0c) * 256;
                coff[p][1] = (i0c * hw + j1c) * 256;
                coff[p][2] = (i1c * hw + j0c) * 256;
                coff[p][3] = (i1c * hw + j1c) * 256;
                const float uw = 1.f - fri, lw = 1.f - frj;
                wgt[p][0] = uw * lw * a;
                wgt[p][1] = uw * frj * a;
                wgt[p][2] = fri * lw * a;
                wgt[p][3] = fri * frj * a;
            }

#pragma unroll
            for (int p = 0; p < 4; ++p) {
                f32x4 buf[8];
                const f32x4* c0 = (const f32x4*)(vb + (size_t)coff[p][0]);
                const f32x4* c1 = (const f32x4*)(vb + (size_t)coff[p][1]);
                const f32x4* c2p = (const f32x4*)(vb + (size_t)coff[p][2]);
                const f32x4* c3 = (const f32x4*)(vb + (size_t)coff[p][3]);
                buf[0] = c0[0]; buf[1] = c0[1];
                buf[2] = c1[0]; buf[3] = c1[1];
                buf[4] = c2p[0]; buf[5] = c2p[1];
                buf[6] = c3[0]; buf[7] = c3[1];
                // Pin all 8 loads in flight: the scheduler cannot sink them
                // past this fence to their uses.
                asm volatile("" : "+v"(buf[0]), "+v"(buf[1]), "+v"(buf[2]), "+v"(buf[3]),
                                  "+v"(buf[4]), "+v"(buf[5]), "+v"(buf[6]), "+v"(buf[7]));
#pragma unroll
                for (int cr = 0; cr < 4; ++cr) {
                    const float wv = wgt[p][cr];
                    const f32x4 u  = buf[cr * 2 + 0];
                    const f32x4 w4 = buf[cr * 2 + 1];
                    acc[0] = fmaf(wv, u.x,  acc[0]);
                    acc[1] = fmaf(wv, u.y,  acc[1]);
                    acc[2] = fmaf(wv, u.z,  acc[2]);
                    acc[3] = fmaf(wv, u.w,  acc[3]);
                    acc[4] = fmaf(wv, w4.x, acc[4]);
                    acc[5] = fmaf(wv, w4.y, acc[5]);
                    acc[6] = fmaf(wv, w4.z, acc[6]);
                    acc[7] = fmaf(wv, w4.w, acc[7]);
                }
            }
        }

        f32x4* sa4 = (f32x4*)(&sAgg[q][h][g * 8]);
        sa4[0] = (f32x4){acc[0], acc[1], acc[2], acc[3]};
        sa4[1] = (f32x4){acc[4], acc[5], acc[6], acc[7]};
    }
    __syncthreads();

    // projection: out channel c2 = tid, head h2 = c2/32; W_val row loads
    // shared across the QPB queries.
    const int c2 = tid, h2 = tid >> 5;
    float s[QPB];
#pragma unroll
    for (int q = 0; q < QPB; ++q) s[q] = b_val[c2];
    for (int k4 = 0; k4 < 64; ++k4) {
        const float w0 = W_val[(k4 * 4 + 0) * 256 + c2];
        const float w1 = W_val[(k4 * 4 + 1) * 256 + c2];
        const float w2 = W_val[(k4 * 4 + 2) * 256 + c2];
        const float w3 = W_val[(k4 * 4 + 3) * 256 + c2];
#pragma unroll
        for (int q = 0; q < QPB; ++q) {
            const f32x4 av = ((const f32x4*)sAgg[q][h2])[k4];
            float t = s[q];
            t = fmaf(av.x, w0, t);
            t = fmaf(av.y, w1, t);
            t = fmaf(av.z, w2, t);
            t = fmaf(av.w, w3, t);
            s[q] = t;
        }
    }
#pragma unroll
    for (int q = 0; q < QPB; ++q)
        val_out[(size_t)(n0 + q) * 256 + c2] = s[q];
}

extern "C" void kernel_launch(void* const* d_in, const int* in_sizes, int n_in,
                              void* d_out, int out_size, void* d_ws, size_t ws_size,
                              hipStream_t stream) {
    const float* query  = (const float*)d_in[0];
    const int*   qoff   = (const int*)d_in[1];
    const float* refp   = (const float*)d_in[2];
    const float* v0     = (const float*)d_in[3];
    const float* v1     = (const float*)d_in[4];
    const float* v2     = (const float*)d_in[5];
    const float* v3     = (const float*)d_in[6];
    const float* W_off  = (const float*)d_in[7];
    const float* b_off  = (const float*)d_in[8];
    const float* W_attn = (const float*)d_in[9];
    const float* b_attn = (const float*)d_in[10];
    const float* W_val  = (const float*)d_in[11];
    const float* b_val  = (const float*)d_in[12];
    const float* W_out  = (const float*)d_in[13];
    const float* b_out  = (const float*)d_in[14];
    float* out = (float*)d_out;

    const int N = in_sizes[0] / 256;   // 16384
    const int n_off = in_sizes[1];     // 2

    float* P1off  = (float*)d_ws;                 // N*256 f32 (offsets)
    float* P1attn = P1off + (size_t)N * 256;      // N*128 f32 (attn logits)

    gemm_nk256<256><<<N / 32, 256, 0, stream>>>(query, W_off, b_off, P1off);
    gemm_nk256<128><<<N / 32, 128, 0, stream>>>(query, W_attn, b_attn, P1attn);
    // softmax fused into sample_agg_proj (reads logits).
    sample_agg_proj<<<N / QPB, 256, 0, stream>>>(P1off, P1attn, refp, qoff, n_off,
                                                 v0, v1, v2, v3, W_val, b_val, out);
    gemm_nk256<256><<<N / 32, 256, 0, stream>>>(out, W_out, b_out, out);
}